// Round 5
// baseline (99.856 us; speedup 1.0000x reference)
//
#include <hip/hip_runtime.h>
#include <stdint.h>

#define ROT(x, r) (((x) << (r)) | ((x) >> (32 - (r))))

// JAX threefry2x32: 20 rounds, rotations [13,15,26,6] / [17,29,16,24]
__host__ __device__ inline void tf_block(uint32_t k0, uint32_t k1,
                                         uint32_t x0, uint32_t x1,
                                         uint32_t& o0, uint32_t& o1) {
  uint32_t ks2 = k0 ^ k1 ^ 0x1BD11BDAu;
  x0 += k0; x1 += k1;
  x0 += x1; x1 = ROT(x1,13); x1 ^= x0;
  x0 += x1; x1 = ROT(x1,15); x1 ^= x0;
  x0 += x1; x1 = ROT(x1,26); x1 ^= x0;
  x0 += x1; x1 = ROT(x1, 6); x1 ^= x0;
  x0 += k1; x1 += ks2 + 1u;
  x0 += x1; x1 = ROT(x1,17); x1 ^= x0;
  x0 += x1; x1 = ROT(x1,29); x1 ^= x0;
  x0 += x1; x1 = ROT(x1,16); x1 ^= x0;
  x0 += x1; x1 = ROT(x1,24); x1 ^= x0;
  x0 += ks2; x1 += k0 + 2u;
  x0 += x1; x1 = ROT(x1,13); x1 ^= x0;
  x0 += x1; x1 = ROT(x1,15); x1 ^= x0;
  x0 += x1; x1 = ROT(x1,26); x1 ^= x0;
  x0 += x1; x1 = ROT(x1, 6); x1 ^= x0;
  x0 += k0; x1 += k1 + 3u;
  x0 += x1; x1 = ROT(x1,17); x1 ^= x0;
  x0 += x1; x1 = ROT(x1,29); x1 ^= x0;
  x0 += x1; x1 = ROT(x1,16); x1 ^= x0;
  x0 += x1; x1 = ROT(x1,24); x1 ^= x0;
  x0 += k1; x1 += ks2 + 4u;
  x0 += x1; x1 = ROT(x1,13); x1 ^= x0;
  x0 += x1; x1 = ROT(x1,15); x1 ^= x0;
  x0 += x1; x1 = ROT(x1,26); x1 ^= x0;
  x0 += x1; x1 = ROT(x1, 6); x1 ^= x0;
  o0 = x0 + ks2;
  o1 = x1 + k0 + 5u;
}

// XLA's EmitTanh f32: clamp to [-9,9], rational poly (unfused mul/add),
// |x| < 0.0004 -> passthrough. Shared CPU/GPU lowering in XLA.
__device__ inline float xla_tanh_f32(float x) {
#pragma clang fp contract(off)
  float ax = fabsf(x);
  float xc = fminf(fmaxf(x, -9.0f), 9.0f);
  float x2 = xc * xc;
  float num = -2.76076847742355e-16f;
  num = x2 * num + 2.00018790482477e-13f;
  num = x2 * num + -8.60467152213735e-11f;
  num = x2 * num + 5.12229709037114e-08f;
  num = x2 * num + 1.48572235717979e-05f;
  num = x2 * num + 6.37261928875436e-04f;
  num = x2 * num + 4.89352455891786e-03f;
  num = xc * num;
  float den = 1.19825839466702e-06f;
  den = x2 * den + 1.18534705686654e-04f;
  den = x2 * den + 2.26843463243900e-03f;
  den = x2 * den + 4.89352518554385e-03f;
  float res = num / den;   // IEEE f32 division (no fast-math)
  return (ax < 0.0004f) ? x : res;
}

// XLA LogisticExpander: logistic(x) = 0.5 + 0.5 * tanh(0.5 * x)
__device__ inline float sigmoid_xla(float s) {
#pragma clang fp contract(off)
  float t = xla_tanh_f32(0.5f * s);
  return 0.5f + 0.5f * t;
}

// Kernel A: prob[n] = sigmoid_xla(5f * w[n])
__global__ void prob_kernel(const float* __restrict__ w, float* __restrict__ prob) {
#pragma clang fp contract(off)
  int n = blockIdx.x * 256 + threadIdx.x;
  float s = 5.0f * w[n];
  prob[n] = sigmoid_xla(s);
}

// Kernel B: EXACT mean via f64. Rows of the [512,65536] prob array are
// identical -> mean = rowsum/65536 (exact power-of-2 scaling), single f32
// rounding at the end. f64 accumulation error ~1e-12 rel: negligible vs
// the f32 rounding interval.
__global__ void rowsum_kernel(const float* __restrict__ prob, float* __restrict__ sc) {
#pragma clang fp contract(off)
  __shared__ double sm[256];
  double acc = 0.0;
  int base = threadIdx.x * 256;
  for (int j = 0; j < 256; ++j) acc += (double)prob[base + j];
  sm[threadIdx.x] = acc;
  __syncthreads();
  for (int off = 128; off > 0; off >>= 1) {
    if (threadIdx.x < off) sm[threadIdx.x] += sm[threadIdx.x + off];
    __syncthreads();
  }
  if (threadIdx.x == 0) {
    double S = sm[0];                         // exact row sum (f64)
    float xbar = (float)(S / 65536.0);        // exact /2^16 in f64, then f32 RN
    float r    = 0.125f / xbar;
    float beta = 0.875f / (1.0f - xbar);
    float le   = (r <= 1.0f) ? 1.0f : 0.0f;
    sc[0] = r; sc[1] = beta; sc[2] = le;
  }
}

// Kernel C: partitionable threefry stream; F32 OUTPUT.
// bits[i] = w0 ^ w1 of block (0, i) under subkey = block (0,1) under key (0,42).
__global__ __launch_bounds__(256) void mask_kernel(
    const float* __restrict__ x, const float* __restrict__ prob,
    const float* __restrict__ sc, float* __restrict__ out,
    uint32_t sk0, uint32_t sk1) {
#pragma clang fp contract(off)
  uint32_t i = blockIdx.x * 256u + threadIdx.x;   // [0, 2^25)
  uint32_t n = i & 65535u;                        // column (row length 65536)
  float p = prob[n];
  float r = sc[0], beta = sc[1], le = sc[2];
  float resc;
  if (le != 0.0f) resc = p * r;
  else            resc = 1.0f - (1.0f - p) * beta;
  uint32_t o0, o1;
  tf_block(sk0, sk1, 0u, i, o0, o1);
  uint32_t bits = o0 ^ o1;
  float u = __uint_as_float((bits >> 9) | 0x3f800000u) - 1.0f;  // exact
  out[i] = (u <= resc) ? x[i] : 0.0f;             // f32 output
}

extern "C" void kernel_launch(void* const* d_in, const int* in_sizes, int n_in,
                              void* d_out, int out_size, void* d_ws, size_t ws_size,
                              hipStream_t stream) {
  const float* x;
  const float* w;
  if (in_sizes[0] == 65536) { w = (const float*)d_in[0]; x = (const float*)d_in[1]; }
  else                      { x = (const float*)d_in[0]; w = (const float*)d_in[1]; }
  float* out = (float*)d_out;                     // FLOAT32 output, 2^25 elements

  float* sc   = (float*)d_ws;                     // scalars
  float* prob = (float*)((char*)d_ws + 256);      // 65536 * 4 B

  // Partitionable split of key(42): subkey = block (0,1) under key (0,42)
  uint32_t s0, s1;
  tf_block(0u, 42u, 0u, 1u, s0, s1);

  prob_kernel<<<256, 256, 0, stream>>>(w, prob);
  rowsum_kernel<<<1, 256, 0, stream>>>(prob, sc);
  mask_kernel<<<131072, 256, 0, stream>>>(x, prob, sc, out, s0, s1);
}

// Round 6
// 90.977 us; speedup vs baseline: 1.0976x; 1.0976x over previous
//
#include <hip/hip_runtime.h>
#include <stdint.h>

#define ROT(x, r) (((x) << (r)) | ((x) >> (32 - (r))))

// JAX threefry2x32: 20 rounds, rotations [13,15,26,6] / [17,29,16,24]
__device__ __forceinline__ void tf_block(uint32_t k0, uint32_t k1,
                                         uint32_t x0, uint32_t x1,
                                         uint32_t& o0, uint32_t& o1) {
  uint32_t ks2 = k0 ^ k1 ^ 0x1BD11BDAu;
  x0 += k0; x1 += k1;
  x0 += x1; x1 = ROT(x1,13); x1 ^= x0;
  x0 += x1; x1 = ROT(x1,15); x1 ^= x0;
  x0 += x1; x1 = ROT(x1,26); x1 ^= x0;
  x0 += x1; x1 = ROT(x1, 6); x1 ^= x0;
  x0 += k1; x1 += ks2 + 1u;
  x0 += x1; x1 = ROT(x1,17); x1 ^= x0;
  x0 += x1; x1 = ROT(x1,29); x1 ^= x0;
  x0 += x1; x1 = ROT(x1,16); x1 ^= x0;
  x0 += x1; x1 = ROT(x1,24); x1 ^= x0;
  x0 += ks2; x1 += k0 + 2u;
  x0 += x1; x1 = ROT(x1,13); x1 ^= x0;
  x0 += x1; x1 = ROT(x1,15); x1 ^= x0;
  x0 += x1; x1 = ROT(x1,26); x1 ^= x0;
  x0 += x1; x1 = ROT(x1, 6); x1 ^= x0;
  x0 += k0; x1 += k1 + 3u;
  x0 += x1; x1 = ROT(x1,17); x1 ^= x0;
  x0 += x1; x1 = ROT(x1,29); x1 ^= x0;
  x0 += x1; x1 = ROT(x1,16); x1 ^= x0;
  x0 += x1; x1 = ROT(x1,24); x1 ^= x0;
  x0 += k1; x1 += ks2 + 4u;
  x0 += x1; x1 = ROT(x1,13); x1 ^= x0;
  x0 += x1; x1 = ROT(x1,15); x1 ^= x0;
  x0 += x1; x1 = ROT(x1,26); x1 ^= x0;
  x0 += x1; x1 = ROT(x1, 6); x1 ^= x0;
  o0 = x0 + ks2;
  o1 = x1 + k0 + 5u;
}

// XLA's EmitTanh f32: clamp to [-9,9], rational poly (unfused mul/add),
// |x| < 0.0004 -> passthrough.
__device__ inline float xla_tanh_f32(float x) {
#pragma clang fp contract(off)
  float ax = fabsf(x);
  float xc = fminf(fmaxf(x, -9.0f), 9.0f);
  float x2 = xc * xc;
  float num = -2.76076847742355e-16f;
  num = x2 * num + 2.00018790482477e-13f;
  num = x2 * num + -8.60467152213735e-11f;
  num = x2 * num + 5.12229709037114e-08f;
  num = x2 * num + 1.48572235717979e-05f;
  num = x2 * num + 6.37261928875436e-04f;
  num = x2 * num + 4.89352455891786e-03f;
  num = xc * num;
  float den = 1.19825839466702e-06f;
  den = x2 * den + 1.18534705686654e-04f;
  den = x2 * den + 2.26843463243900e-03f;
  den = x2 * den + 4.89352518554385e-03f;
  float res = num / den;   // IEEE f32 division (no fast-math)
  return (ax < 0.0004f) ? x : res;
}

// XLA LogisticExpander: logistic(x) = 0.5 + 0.5 * tanh(0.5 * x)
__device__ inline float sigmoid_xla(float s) {
#pragma clang fp contract(off)
  float t = xla_tanh_f32(0.5f * s);
  return 0.5f + 0.5f * t;
}

// Kernel A: prob[n] = sigmoid_xla(5f * w[n])
__global__ void prob_kernel(const float* __restrict__ w, float* __restrict__ prob) {
#pragma clang fp contract(off)
  int n = blockIdx.x * 256 + threadIdx.x;
  float s = 5.0f * w[n];
  prob[n] = sigmoid_xla(s);
}

// Kernel B: exact f64 row mean -> r/beta/le -> integer thresholds.
// u = m*2^-23 exactly (m = bits>>9), so (u <= resc) <=> (m <= floor(resc*2^23)),
// computed exactly in f64 (f32->f64 exact, *2^23 exact, floor exact).
__global__ void rowsum_thresh_kernel(const float* __restrict__ prob,
                                     uint32_t* __restrict__ thresh) {
#pragma clang fp contract(off)
  __shared__ double sm[256];
  __shared__ float sv[3];
  double acc = 0.0;
  for (int j = 0; j < 256; ++j) acc += (double)prob[j * 256 + threadIdx.x];
  sm[threadIdx.x] = acc;
  __syncthreads();
  for (int off = 128; off > 0; off >>= 1) {
    if (threadIdx.x < off) sm[threadIdx.x] += sm[threadIdx.x + off];
    __syncthreads();
  }
  if (threadIdx.x == 0) {
    double S = sm[0];                         // exact row sum (f64)
    float xbar = (float)(S / 65536.0);        // exact /2^16, then single f32 RN
    float r    = 0.125f / xbar;
    float beta = 0.875f / (1.0f - xbar);
    sv[0] = r; sv[1] = beta; sv[2] = (r <= 1.0f) ? 1.0f : 0.0f;
  }
  __syncthreads();
  float r = sv[0], beta = sv[1], le = sv[2];
  for (int j = 0; j < 256; ++j) {
    int n = j * 256 + threadIdx.x;
    float p = prob[n];
    float resc = (le != 0.0f) ? (p * r) : (1.0f - (1.0f - p) * beta);
    double f = floor((double)resc * 8388608.0);     // exact
    if (f > 8388607.0) f = 8388607.0;               // all-pass clamp (m < 2^23)
    thresh[n] = (uint32_t)f;
  }
}

// Kernel C: 8 elements/thread, 8 independent threefry chains (ILP),
// float4 x2 loads/stores, integer mask compare.
__global__ __launch_bounds__(256) void mask_kernel(
    const float4* __restrict__ x4, const uint32_t* __restrict__ thresh,
    float4* __restrict__ out4, uint32_t sk0, uint32_t sk1) {
  uint32_t t  = blockIdx.x * 256u + threadIdx.x;   // [0, 2^22)
  uint32_t i0 = t * 8u;                            // flat element base
  uint32_t n0 = i0 & 65535u;                       // column base (mult of 8)
  const uint4* tp = reinterpret_cast<const uint4*>(thresh + n0);
  uint4 Ta = tp[0];
  uint4 Tb = tp[1];
  float4 xa = x4[2u * t];
  float4 xb = x4[2u * t + 1u];
  uint32_t m[8];
#pragma unroll
  for (int j = 0; j < 8; ++j) {
    uint32_t o0, o1;
    tf_block(sk0, sk1, 0u, i0 + (uint32_t)j, o0, o1);
    m[j] = (o0 ^ o1) >> 9;
  }
  float4 oa, ob;
  oa.x = (m[0] <= Ta.x) ? xa.x : 0.0f;
  oa.y = (m[1] <= Ta.y) ? xa.y : 0.0f;
  oa.z = (m[2] <= Ta.z) ? xa.z : 0.0f;
  oa.w = (m[3] <= Ta.w) ? xa.w : 0.0f;
  ob.x = (m[4] <= Tb.x) ? xb.x : 0.0f;
  ob.y = (m[5] <= Tb.y) ? xb.y : 0.0f;
  ob.z = (m[6] <= Tb.z) ? xb.z : 0.0f;
  ob.w = (m[7] <= Tb.w) ? xb.w : 0.0f;
  out4[2u * t]      = oa;
  out4[2u * t + 1u] = ob;
}

extern "C" void kernel_launch(void* const* d_in, const int* in_sizes, int n_in,
                              void* d_out, int out_size, void* d_ws, size_t ws_size,
                              hipStream_t stream) {
  const float* x;
  const float* w;
  if (in_sizes[0] == 65536) { w = (const float*)d_in[0]; x = (const float*)d_in[1]; }
  else                      { x = (const float*)d_in[0]; w = (const float*)d_in[1]; }
  float* out = (float*)d_out;                     // f32 output, 2^25 elements

  float*    prob   = (float*)d_ws;                         // 256 KiB
  uint32_t* thresh = (uint32_t*)((char*)d_ws + 65536 * 4); // 256 KiB

  // Partitionable split of key(42): subkey = block (0,1) under key (0,42)
  uint32_t s0, s1;
  tf_block_host:;
  {
    uint32_t k0 = 0u, k1 = 42u, x0 = 0u, x1 = 1u;
    uint32_t ks2 = k0 ^ k1 ^ 0x1BD11BDAu;
    x0 += k0; x1 += k1;
    x0 += x1; x1 = ROT(x1,13); x1 ^= x0;
    x0 += x1; x1 = ROT(x1,15); x1 ^= x0;
    x0 += x1; x1 = ROT(x1,26); x1 ^= x0;
    x0 += x1; x1 = ROT(x1, 6); x1 ^= x0;
    x0 += k1; x1 += ks2 + 1u;
    x0 += x1; x1 = ROT(x1,17); x1 ^= x0;
    x0 += x1; x1 = ROT(x1,29); x1 ^= x0;
    x0 += x1; x1 = ROT(x1,16); x1 ^= x0;
    x0 += x1; x1 = ROT(x1,24); x1 ^= x0;
    x0 += ks2; x1 += k0 + 2u;
    x0 += x1; x1 = ROT(x1,13); x1 ^= x0;
    x0 += x1; x1 = ROT(x1,15); x1 ^= x0;
    x0 += x1; x1 = ROT(x1,26); x1 ^= x0;
    x0 += x1; x1 = ROT(x1, 6); x1 ^= x0;
    x0 += k0; x1 += k1 + 3u;
    x0 += x1; x1 = ROT(x1,17); x1 ^= x0;
    x0 += x1; x1 = ROT(x1,29); x1 ^= x0;
    x0 += x1; x1 = ROT(x1,16); x1 ^= x0;
    x0 += x1; x1 = ROT(x1,24); x1 ^= x0;
    x0 += k1; x1 += ks2 + 4u;
    x0 += x1; x1 = ROT(x1,13); x1 ^= x0;
    x0 += x1; x1 = ROT(x1,15); x1 ^= x0;
    x0 += x1; x1 = ROT(x1,26); x1 ^= x0;
    x0 += x1; x1 = ROT(x1, 6); x1 ^= x0;
    s0 = x0 + ks2;
    s1 = x1 + k0 + 5u;
  }

  prob_kernel<<<256, 256, 0, stream>>>(w, prob);
  rowsum_thresh_kernel<<<1, 256, 0, stream>>>(prob, thresh);
  mask_kernel<<<16384, 256, 0, stream>>>((const float4*)x, thresh, (float4*)out, s0, s1);
}

// Round 7
// 75.904 us; speedup vs baseline: 1.3156x; 1.1986x over previous
//
#include <hip/hip_runtime.h>
#include <stdint.h>

#define ROT(x, r) (((x) << (r)) | ((x) >> (32 - (r))))

#define TF_BODY(k0, k1, x0, x1, o0, o1)                                  \
  {                                                                      \
    uint32_t ks2 = (k0) ^ (k1) ^ 0x1BD11BDAu;                            \
    x0 += (k0); x1 += (k1);                                              \
    x0 += x1; x1 = ROT(x1,13); x1 ^= x0;                                 \
    x0 += x1; x1 = ROT(x1,15); x1 ^= x0;                                 \
    x0 += x1; x1 = ROT(x1,26); x1 ^= x0;                                 \
    x0 += x1; x1 = ROT(x1, 6); x1 ^= x0;                                 \
    x0 += (k1); x1 += ks2 + 1u;                                          \
    x0 += x1; x1 = ROT(x1,17); x1 ^= x0;                                 \
    x0 += x1; x1 = ROT(x1,29); x1 ^= x0;                                 \
    x0 += x1; x1 = ROT(x1,16); x1 ^= x0;                                 \
    x0 += x1; x1 = ROT(x1,24); x1 ^= x0;                                 \
    x0 += ks2; x1 += (k0) + 2u;                                          \
    x0 += x1; x1 = ROT(x1,13); x1 ^= x0;                                 \
    x0 += x1; x1 = ROT(x1,15); x1 ^= x0;                                 \
    x0 += x1; x1 = ROT(x1,26); x1 ^= x0;                                 \
    x0 += x1; x1 = ROT(x1, 6); x1 ^= x0;                                 \
    x0 += (k0); x1 += (k1) + 3u;                                         \
    x0 += x1; x1 = ROT(x1,17); x1 ^= x0;                                 \
    x0 += x1; x1 = ROT(x1,29); x1 ^= x0;                                 \
    x0 += x1; x1 = ROT(x1,16); x1 ^= x0;                                 \
    x0 += x1; x1 = ROT(x1,24); x1 ^= x0;                                 \
    x0 += (k1); x1 += ks2 + 4u;                                          \
    x0 += x1; x1 = ROT(x1,13); x1 ^= x0;                                 \
    x0 += x1; x1 = ROT(x1,15); x1 ^= x0;                                 \
    x0 += x1; x1 = ROT(x1,26); x1 ^= x0;                                 \
    x0 += x1; x1 = ROT(x1, 6); x1 ^= x0;                                 \
    o0 = x0 + ks2;                                                       \
    o1 = x1 + (k0) + 5u;                                                 \
  }

__device__ __forceinline__ void tf_block(uint32_t k0, uint32_t k1,
                                         uint32_t x0, uint32_t x1,
                                         uint32_t& o0, uint32_t& o1) {
  TF_BODY(k0, k1, x0, x1, o0, o1)
}

// XLA's EmitTanh f32: clamp to [-9,9], rational poly (unfused mul/add),
// |x| < 0.0004 -> passthrough.
__device__ inline float xla_tanh_f32(float x) {
#pragma clang fp contract(off)
  float ax = fabsf(x);
  float xc = fminf(fmaxf(x, -9.0f), 9.0f);
  float x2 = xc * xc;
  float num = -2.76076847742355e-16f;
  num = x2 * num + 2.00018790482477e-13f;
  num = x2 * num + -8.60467152213735e-11f;
  num = x2 * num + 5.12229709037114e-08f;
  num = x2 * num + 1.48572235717979e-05f;
  num = x2 * num + 6.37261928875436e-04f;
  num = x2 * num + 4.89352455891786e-03f;
  num = xc * num;
  float den = 1.19825839466702e-06f;
  den = x2 * den + 1.18534705686654e-04f;
  den = x2 * den + 2.26843463243900e-03f;
  den = x2 * den + 4.89352518554385e-03f;
  float res = num / den;   // IEEE f32 division (no fast-math)
  return (ax < 0.0004f) ? x : res;
}

// XLA LogisticExpander: logistic(x) = 0.5 + 0.5 * tanh(0.5 * x)
__device__ inline float sigmoid_xla(float s) {
#pragma clang fp contract(off)
  float t = xla_tanh_f32(0.5f * s);
  return 0.5f + 0.5f * t;
}

// Kernel A: prob[n] = sigmoid_xla(5f*w[n]) + per-block f64 partial sum (256 blocks)
__global__ void prob_sum_kernel(const float* __restrict__ w, float* __restrict__ prob,
                                double* __restrict__ partial) {
#pragma clang fp contract(off)
  __shared__ double sm[256];
  int n = blockIdx.x * 256 + threadIdx.x;
  float s = 5.0f * w[n];
  float p = sigmoid_xla(s);
  prob[n] = p;
  sm[threadIdx.x] = (double)p;
  __syncthreads();
  for (int off = 128; off > 0; off >>= 1) {
    if (threadIdx.x < off) sm[threadIdx.x] += sm[threadIdx.x + off];
    __syncthreads();
  }
  if (threadIdx.x == 0) partial[blockIdx.x] = sm[0];
}

// Kernel B: final f64 reduce (1 block) -> r/beta/le scalars
__global__ void final_kernel(const double* __restrict__ partial, float* __restrict__ sc) {
#pragma clang fp contract(off)
  __shared__ double sm[256];
  sm[threadIdx.x] = partial[threadIdx.x];
  __syncthreads();
  for (int off = 128; off > 0; off >>= 1) {
    if (threadIdx.x < off) sm[threadIdx.x] += sm[threadIdx.x + off];
    __syncthreads();
  }
  if (threadIdx.x == 0) {
    double S = sm[0];                         // exact row sum (f64)
    float xbar = (float)(S / 65536.0);        // exact /2^16, then single f32 RN
    float r    = 0.125f / xbar;
    float beta = 0.875f / (1.0f - xbar);
    sc[0] = r; sc[1] = beta; sc[2] = (r <= 1.0f) ? 1.0f : 0.0f;
  }
}

// Kernel C: integer thresholds, one column per thread (256 blocks).
// u = m*2^-23 exactly (m = bits>>9), so (u <= resc) <=> (m <= floor(resc*2^23)).
__global__ void thresh_kernel(const float* __restrict__ prob,
                              const float* __restrict__ sc,
                              uint32_t* __restrict__ thresh) {
#pragma clang fp contract(off)
  int n = blockIdx.x * 256 + threadIdx.x;
  float r = sc[0], beta = sc[1], le = sc[2];
  float p = prob[n];
  float resc = (le != 0.0f) ? (p * r) : (1.0f - (1.0f - p) * beta);
  double f = floor((double)resc * 8388608.0);     // exact
  if (f > 8388607.0) f = 8388607.0;               // all-pass clamp (m < 2^23)
  thresh[n] = (uint32_t)f;
}

// Kernel D: 8 elements/thread, 8 independent threefry chains (ILP),
// float4 x2 loads/stores, integer mask compare.
__global__ __launch_bounds__(256) void mask_kernel(
    const float4* __restrict__ x4, const uint32_t* __restrict__ thresh,
    float4* __restrict__ out4, uint32_t sk0, uint32_t sk1) {
  uint32_t t  = blockIdx.x * 256u + threadIdx.x;   // [0, 2^22)
  uint32_t i0 = t * 8u;                            // flat element base
  uint32_t n0 = i0 & 65535u;                       // column base (mult of 8)
  const uint4* tp = reinterpret_cast<const uint4*>(thresh + n0);
  uint4 Ta = tp[0];
  uint4 Tb = tp[1];
  float4 xa = x4[2u * t];
  float4 xb = x4[2u * t + 1u];
  uint32_t m[8];
#pragma unroll
  for (int j = 0; j < 8; ++j) {
    uint32_t o0, o1;
    tf_block(sk0, sk1, 0u, i0 + (uint32_t)j, o0, o1);
    m[j] = (o0 ^ o1) >> 9;
  }
  float4 oa, ob;
  oa.x = (m[0] <= Ta.x) ? xa.x : 0.0f;
  oa.y = (m[1] <= Ta.y) ? xa.y : 0.0f;
  oa.z = (m[2] <= Ta.z) ? xa.z : 0.0f;
  oa.w = (m[3] <= Ta.w) ? xa.w : 0.0f;
  ob.x = (m[4] <= Tb.x) ? xb.x : 0.0f;
  ob.y = (m[5] <= Tb.y) ? xb.y : 0.0f;
  ob.z = (m[6] <= Tb.z) ? xb.z : 0.0f;
  ob.w = (m[7] <= Tb.w) ? xb.w : 0.0f;
  out4[2u * t]      = oa;
  out4[2u * t + 1u] = ob;
}

extern "C" void kernel_launch(void* const* d_in, const int* in_sizes, int n_in,
                              void* d_out, int out_size, void* d_ws, size_t ws_size,
                              hipStream_t stream) {
  const float* x;
  const float* w;
  if (in_sizes[0] == 65536) { w = (const float*)d_in[0]; x = (const float*)d_in[1]; }
  else                      { x = (const float*)d_in[0]; w = (const float*)d_in[1]; }
  float* out = (float*)d_out;                     // f32 output, 2^25 elements

  float*    prob    = (float*)d_ws;                          // 256 KiB
  uint32_t* thresh  = (uint32_t*)((char*)d_ws + 65536 * 4);  // 256 KiB
  double*   partial = (double*)((char*)d_ws + 2 * 65536 * 4);// 2 KiB
  float*    sc      = (float*)((char*)d_ws + 2 * 65536 * 4 + 2048);

  // Partitionable split of key(42): subkey = block (0,1) under key (0,42)
  uint32_t s0, s1;
  {
    uint32_t k0 = 0u, k1 = 42u, x0 = 0u, x1 = 1u, o0, o1;
    TF_BODY(k0, k1, x0, x1, o0, o1)
    s0 = o0; s1 = o1;
  }

  prob_sum_kernel<<<256, 256, 0, stream>>>(w, prob, partial);
  final_kernel<<<1, 256, 0, stream>>>(partial, sc);
  thresh_kernel<<<256, 256, 0, stream>>>(prob, sc, thresh);
  mask_kernel<<<16384, 256, 0, stream>>>((const float4*)x, thresh, (float4*)out, s0, s1);
}